// Round 16
// baseline (146.997 us; speedup 1.0000x reference)
//
#include <hip/hip_runtime.h>
#include <math.h>

#define NN 100000
#define NE 1600000
#define D 64
#define DM 32
#define BK 128                       // nodes per bucket
#define NBUCK ((NN + BK - 1) / BK)   // 782
#define CAP 2560                     // fixed edge capacity per bucket (mean 2048, 11 sigma)
#define MS_CHUNK 4096
#define N_MS ((NE + MS_CHUNK - 1) / MS_CHUNK)   // 391
#define NTILE ((NN + 63) / 64)       // 1563 blocks for the MFMA layer kernel

typedef unsigned int uint32;
typedef unsigned short ushort16;
typedef __attribute__((ext_vector_type(8))) short short8v;   // 8 bf16 (4 VGPR)
typedef __attribute__((ext_vector_type(4))) float float4v;
typedef __attribute__((ext_vector_type(4))) uint32 uint4v;

__device__ __forceinline__ ushort16 f2bf(float f) {
    unsigned u = __float_as_uint(f);
    unsigned r = (u + 0x7FFF + ((u >> 16) & 1)) >> 16;   // round-nearest-even
    return (ushort16)r;
}
__device__ __forceinline__ float bfLo(uint32 u) { return __uint_as_float(u << 16); }
__device__ __forceinline__ float bfHi(uint32 u) { return __uint_as_float(u & 0xFFFF0000u); }

// ---------- fused prep: x->bf16 cvt | weight fragments | cursor init ----------
// Heterogeneous grid: blocks 0..1023 convert x, 1024..1055 build B-frags,
// block 1056 initializes bucket cursors. All three are independent.
__global__ __launch_bounds__(256) void prep_kernel(
    const float4* __restrict__ xin, ushort4* __restrict__ xoutb, int n4,
    const float* __restrict__ W1l, const float* __restrict__ W1r,
    const float* __restrict__ W2l, const float* __restrict__ W2r,
    const float* __restrict__ Wf1,
    ushort16* __restrict__ bfragL1, ushort16* __restrict__ bfragL2,
    ushort16* __restrict__ b2frag,
    int* __restrict__ bucketCursor)
{
    int b = blockIdx.x;
    if (b < 1024) {
        for (int i = b * 256 + threadIdx.x; i < n4; i += 1024 * 256) {
            float4 v = xin[i];
            ushort4 o;
            o.x = f2bf(v.x); o.y = f2bf(v.y); o.z = f2bf(v.z); o.w = f2bf(v.w);
            xoutb[i] = o;
        }
    } else if (b < 1056) {
        int tid = (b - 1024) * 256 + threadIdx.x;   // 0..8191
        {
            int idx = tid;
            int i = idx & 7, l = (idx >> 3) & 63, jt = (idx >> 9) & 3, kb = idx >> 11;
            int k = kb * 32 + (l >> 4) * 8 + i;
            int j = jt * 16 + (l & 15);
            float v1 = (k < 64) ? W1l[k * 64 + j] : W1r[(k - 64) * 64 + j];
            float v2 = (k < 64) ? W2l[k * 64 + j] : W2r[(k - 64) * 64 + j];
            bfragL1[idx] = f2bf(v1);
            bfragL2[idx] = f2bf(v2);
        }
        if (tid < 2048) {
            int idx = tid;
            int i = idx & 7, l = (idx >> 3) & 63, jt2 = (idx >> 9) & 1, kb2 = idx >> 10;
            int k = kb2 * 32 + (l >> 4) * 8 + i;
            int j = jt2 * 16 + (l & 15);
            b2frag[idx] = f2bf(Wf1[k * 32 + j]);
        }
    } else {
        for (int t = threadIdx.x; t < NBUCK; t += 256)
            bucketCursor[t] = t * CAP;
    }
}

// ---------- multisplit: edges -> bucket-grouped packed runs ----------
// 1024 threads/block (16 waves); per block: LDS int hist -> one global
// reservation per bucket -> contiguous packed run writes.
__global__ __launch_bounds__(1024) void multisplit_kernel(
    const int* __restrict__ src, const int* __restrict__ dst,
    int* __restrict__ bucketCursor, uint32* __restrict__ edgesPacked)
{
    __shared__ int lh[NBUCK];
    __shared__ int lbase[NBUCK];
    int t = threadIdx.x;
    if (t < NBUCK) lh[t] = 0;
    __syncthreads();
    int base = blockIdx.x * MS_CHUNK;
#pragma unroll
    for (int i = 0; i < MS_CHUNK / 1024; ++i) {
        int e = base + i * 1024 + t;
        if (e < NE) atomicAdd(&lh[dst[e] >> 7], 1);
    }
    __syncthreads();
    if (t < NBUCK) {
        int c = lh[t];
        lbase[t] = c ? atomicAdd(&bucketCursor[t], c) : 0;
        lh[t] = 0;                       // reuse as rank
    }
    __syncthreads();
#pragma unroll
    for (int i = 0; i < MS_CHUNK / 1024; ++i) {
        int e = base + i * 1024 + t;
        if (e < NE) {
            int d = dst[e];
            int b = d >> 7;
            int r = atomicAdd(&lh[b], 1);
            edgesPacked[lbase[b] + r] = ((uint32)src[e] << 7) | (uint32)(d & 127);
        }
    }
}

// ---------- reorder + per-node CSR build (bucket-local) ----------
__global__ __launch_bounds__(256) void reorder_csr_kernel(
    const uint32* __restrict__ edgesPacked,
    const int* __restrict__ bucketEnd,
    int* __restrict__ rowBeg, int* __restrict__ deg,
    int* __restrict__ sortedSrc)
{
    __shared__ int lcnt[BK];
    __shared__ int sc[BK];
    __shared__ int rowBegL[BK];
    int t = threadIdx.x;
    int b = blockIdx.x;
    int eBeg = b * CAP, eEnd = bucketEnd[b];

    if (t < BK) lcnt[t] = 0;
    __syncthreads();
    for (int e = eBeg + t; e < eEnd; e += 256)
        atomicAdd(&lcnt[edgesPacked[e] & 127], 1);
    __syncthreads();

    int myCnt = (t < BK) ? lcnt[t] : 0;
    if (t < BK) sc[t] = myCnt;
    __syncthreads();
#pragma unroll
    for (int off = 1; off < BK; off <<= 1) {
        int v = 0;
        if (t < BK && t >= off) v = sc[t - off];
        __syncthreads();
        if (t < BK) sc[t] += v;
        __syncthreads();
    }
    if (t < BK) {
        int excl = sc[t] - myCnt;
        int begHere = eBeg + excl;
        rowBegL[t] = begHere;
        int node = b * BK + t;
        if (node < NN) {
            rowBeg[node] = begHere;
            deg[node] = myCnt;
        }
        lcnt[t] = 0;                     // reuse as rank counter
    }
    __syncthreads();

    for (int e = eBeg + t; e < eEnd; e += 256) {
        uint32 u = edgesPacked[e];
        int rel = (int)(u & 127);
        int rank = atomicAdd(&lcnt[rel], 1);
        sortedSrc[rowBegL[rel] + rank] = (int)(u >> 7);
    }
}

// ---------- gather-mean v3: direct broadcast index loads ----------
// One wave per node; group g = lane>>4 handles edge 4i+g, slot q = lane&15
// holds uint2 = features 4q..4q+3. Index load: 16 lanes/group read the SAME
// address ss[beg+4i+g] (1 coalesced VMEM, lane broadcast, L1-resident).
// No ds_bpermute, no 64-edge chunk staging. 16 edges in flight.
__global__ __launch_bounds__(256) void gather_mean_kernel(
    const uint2* __restrict__ hb2,     // bf16 rows as uint2, 16 per node
    const int* __restrict__ rowBeg, const int* __restrict__ deg,
    const int* __restrict__ ss,
    uint2* __restrict__ meanb2,        // packed bf16 mean, 16 uint2/node
    int n)
{
    int lane = threadIdx.x & 63;
    int wid = threadIdx.x >> 6;
    int q = lane & 15;
    int g = lane >> 4;

    for (int node = blockIdx.x * 4 + wid; node < n; node += gridDim.x * 4) {
        int dg = deg[node];
        const int* ep = ss + rowBeg[node];
        float a0 = 0.f, a1 = 0.f, a2 = 0.f, a3 = 0.f;
        int nq = dg >> 2;                  // quads of edges
        int i = 0;
        for (; i + 4 <= nq; i += 4) {      // 16 edges in flight
            int s0 = ep[(i + 0) * 4 + g];
            int s1 = ep[(i + 1) * 4 + g];
            int s2 = ep[(i + 2) * 4 + g];
            int s3 = ep[(i + 3) * 4 + g];
            uint2 u0 = hb2[(size_t)s0 * 16 + q];
            uint2 u1 = hb2[(size_t)s1 * 16 + q];
            uint2 u2 = hb2[(size_t)s2 * 16 + q];
            uint2 u3 = hb2[(size_t)s3 * 16 + q];
            a0 += (bfLo(u0.x) + bfLo(u1.x)) + (bfLo(u2.x) + bfLo(u3.x));
            a1 += (bfHi(u0.x) + bfHi(u1.x)) + (bfHi(u2.x) + bfHi(u3.x));
            a2 += (bfLo(u0.y) + bfLo(u1.y)) + (bfLo(u2.y) + bfLo(u3.y));
            a3 += (bfHi(u0.y) + bfHi(u1.y)) + (bfHi(u2.y) + bfHi(u3.y));
        }
        for (; i < nq; ++i) {
            int s = ep[i * 4 + g];
            uint2 u = hb2[(size_t)s * 16 + q];
            a0 += bfLo(u.x); a1 += bfHi(u.x);
            a2 += bfLo(u.y); a3 += bfHi(u.y);
        }
        int rem = dg & 3;
        if (rem && g < rem) {
            int s = ep[nq * 4 + g];
            uint2 u = hb2[(size_t)s * 16 + q];
            a0 += bfLo(u.x); a1 += bfHi(u.x);
            a2 += bfLo(u.y); a3 += bfHi(u.y);
        }
        // reduce across the 4 lane-groups
        a0 += __shfl_xor(a0, 16); a0 += __shfl_xor(a0, 32);
        a1 += __shfl_xor(a1, 16); a1 += __shfl_xor(a1, 32);
        a2 += __shfl_xor(a2, 16); a2 += __shfl_xor(a2, 32);
        a3 += __shfl_xor(a3, 16); a3 += __shfl_xor(a3, 32);
        if (lane < 16) {
            float inv = (dg > 0) ? 1.0f / (float)dg : 0.0f;
            uint2 o;
            o.x = (uint32)f2bf(a0 * inv) | ((uint32)f2bf(a1 * inv) << 16);
            o.y = (uint32)f2bf(a2 * inv) | ((uint32)f2bf(a3 * inv) << 16);
            meanb2[(size_t)node * 16 + q] = o;
        }
    }
}

// ---------- MFMA SAGE layer (R12-proven) ----------
template <int WITH_MLP>
__global__ __launch_bounds__(256) void sage_mfma_kernel(
    const ushort16* __restrict__ rootb,      // bf16 root rows [n][64]
    const uint32* __restrict__ meanb32,      // packed bf16 mean [n][32]
    const ushort16* __restrict__ bfrag,      // 8192 bf16 lane-ordered
    const ushort16* __restrict__ b2frag,     // 2048 bf16 (MLP)
    const float* __restrict__ bl,
    const float* __restrict__ bf1, const float* __restrict__ Wf2,
    const float* __restrict__ bf2,
    ushort16* __restrict__ houtb,            // bf16 layer out (WITH_MLP=0)
    float* __restrict__ outp,                // final out (WITH_MLP=1)
    int n)
{
    __shared__ ushort16 h2L[WITH_MLP ? (64 * 64) : 1];

    int lane = threadIdx.x & 63;
    int w = threadIdx.x >> 6;           // wave 0..3
    int c = lane & 15;                  // col / A-row
    int g = lane >> 4;                  // k-group
    int blkBase = blockIdx.x * 64;

    int arow = blkBase + w * 16 + c;
    bool aval = (arow < n);
    uint4v zero4 = {0u, 0u, 0u, 0u};
    const uint32* mrow = meanb32 + (size_t)arow * 32;
    const uint32* xrow = (const uint32*)rootb + (size_t)arow * 32;
    uint4v am0 = aval ? *(const uint4v*)(mrow + g * 4) : zero4;
    uint4v am1 = aval ? *(const uint4v*)(mrow + 16 + g * 4) : zero4;
    uint4v ax0 = aval ? *(const uint4v*)(xrow + g * 4) : zero4;
    uint4v ax1 = aval ? *(const uint4v*)(xrow + 16 + g * 4) : zero4;
    short8v a0 = __builtin_bit_cast(short8v, am0);
    short8v a1 = __builtin_bit_cast(short8v, am1);
    short8v a2 = __builtin_bit_cast(short8v, ax0);
    short8v a3 = __builtin_bit_cast(short8v, ax1);

    const short8v* bf = (const short8v*)bfrag;
    float4v acc[4];
#pragma unroll
    for (int jt = 0; jt < 4; ++jt) acc[jt] = (float4v){0.f, 0.f, 0.f, 0.f};
#pragma unroll
    for (int jt = 0; jt < 4; ++jt) {
        acc[jt] = __builtin_amdgcn_mfma_f32_16x16x32_bf16(a0, bf[(0 * 4 + jt) * 64 + lane], acc[jt], 0, 0, 0);
        acc[jt] = __builtin_amdgcn_mfma_f32_16x16x32_bf16(a1, bf[(1 * 4 + jt) * 64 + lane], acc[jt], 0, 0, 0);
        acc[jt] = __builtin_amdgcn_mfma_f32_16x16x32_bf16(a2, bf[(2 * 4 + jt) * 64 + lane], acc[jt], 0, 0, 0);
        acc[jt] = __builtin_amdgcn_mfma_f32_16x16x32_bf16(a3, bf[(3 * 4 + jt) * 64 + lane], acc[jt], 0, 0, 0);
    }

    float blv[4];
#pragma unroll
    for (int jt = 0; jt < 4; ++jt) blv[jt] = bl[jt * 16 + c];

    if (!WITH_MLP) {
#pragma unroll
        for (int jt = 0; jt < 4; ++jt) {
#pragma unroll
            for (int r = 0; r < 4; ++r) {
                int nd = blkBase + w * 16 + g * 4 + r;
                if (nd < n)
                    houtb[(size_t)nd * 64 + jt * 16 + c] =
                        f2bf(fmaxf(acc[jt][r] + blv[jt], 0.0f));
            }
        }
    } else {
#pragma unroll
        for (int jt = 0; jt < 4; ++jt) {
            int j = jt * 16 + c;
#pragma unroll
            for (int r = 0; r < 4; ++r) {
                int row = w * 16 + g * 4 + r;
                ushort16 hv = f2bf(fmaxf(acc[jt][r] + blv[jt], 0.0f));
                h2L[row * 64 + (((j >> 3) ^ (row & 7)) << 3) + (j & 7)] = hv;
            }
        }
        __syncthreads();

        int arow2 = w * 16 + c;
        short8v a2f[2];
#pragma unroll
        for (int kb2 = 0; kb2 < 2; ++kb2) {
            int chunk = (kb2 * 4 + g) ^ (arow2 & 7);
            a2f[kb2] = *(const short8v*)&h2L[arow2 * 64 + chunk * 8];
        }
        const short8v* b2f = (const short8v*)b2frag;
        float4v acc2[2];
#pragma unroll
        for (int jt2 = 0; jt2 < 2; ++jt2) acc2[jt2] = (float4v){0.f, 0.f, 0.f, 0.f};
#pragma unroll
        for (int jt2 = 0; jt2 < 2; ++jt2) {
            acc2[jt2] = __builtin_amdgcn_mfma_f32_16x16x32_bf16(a2f[0], b2f[(0 * 2 + jt2) * 64 + lane], acc2[jt2], 0, 0, 0);
            acc2[jt2] = __builtin_amdgcn_mfma_f32_16x16x32_bf16(a2f[1], b2f[(1 * 2 + jt2) * 64 + lane], acc2[jt2], 0, 0, 0);
        }

        float bf1v[2], f2v[2];
#pragma unroll
        for (int jt2 = 0; jt2 < 2; ++jt2) {
            bf1v[jt2] = bf1[jt2 * 16 + c];
            f2v[jt2]  = Wf2[jt2 * 16 + c];
        }
        float bias2 = bf2[0];

        float pv[4];
#pragma unroll
        for (int r = 0; r < 4; ++r) {
            float t = 0.0f;
#pragma unroll
            for (int jt2 = 0; jt2 < 2; ++jt2) {
                float h3 = fmaxf(acc2[jt2][r] + bf1v[jt2], 0.0f);
                t += h3 * f2v[jt2];
            }
#pragma unroll
            for (int off = 1; off <= 8; off <<= 1) t += __shfl_xor(t, off);
            pv[r] = t;
        }
        if (c == 0) {
#pragma unroll
            for (int r = 0; r < 4; ++r) {
                int nd = blkBase + w * 16 + g * 4 + r;
                if (nd < n)
                    outp[nd] = 1.0f / (1.0f + expf(-(pv[r] + bias2)));
            }
        }
    }
}

extern "C" void kernel_launch(void* const* d_in, const int* in_sizes, int n_in,
                              void* d_out, int out_size, void* d_ws, size_t ws_size,
                              hipStream_t stream)
{
    const float* x   = (const float*)d_in[0];
    const int*   ei  = (const int*)d_in[1];
    const float* W1l = (const float*)d_in[2];
    const float* b1l = (const float*)d_in[3];
    const float* W1r = (const float*)d_in[4];
    const float* W2l = (const float*)d_in[5];
    const float* b2l = (const float*)d_in[6];
    const float* W2r = (const float*)d_in[7];
    const float* Wf1 = (const float*)d_in[8];
    const float* bf1 = (const float*)d_in[9];
    const float* Wf2 = (const float*)d_in[10];
    const float* bf2 = (const float*)d_in[11];
    float* out = (float*)d_out;

    const int* src = ei;            // edge_index[0]
    const int* dst = ei + NE;       // edge_index[1]

    char* ws = (char*)d_ws;
    size_t off = 0;
    auto alloc = [&](size_t bytes) {
        char* p = ws + off;
        off = (off + bytes + 255) & ~(size_t)255;
        return p;
    };
    int* bucketCursor = (int*)alloc((size_t)NBUCK * sizeof(int));
    int* rowBeg       = (int*)alloc((size_t)NN * sizeof(int));
    int* deg          = (int*)alloc((size_t)NN * sizeof(int));
    uint32* edgesPacked = (uint32*)alloc((size_t)NBUCK * CAP * sizeof(uint32));
    int* sortedSrc      = (int*)alloc((size_t)NBUCK * CAP * sizeof(int));
    ushort16* xb    = (ushort16*)alloc((size_t)NN * D * sizeof(ushort16));
    ushort16* h1b   = (ushort16*)alloc((size_t)NN * D * sizeof(ushort16));
    uint32*   meanb = (uint32*)alloc((size_t)NN * (D / 2) * sizeof(uint32));
    ushort16* bfragL1 = (ushort16*)alloc(8192 * sizeof(ushort16));
    ushort16* bfragL2 = (ushort16*)alloc(8192 * sizeof(ushort16));
    ushort16* b2frag  = (ushort16*)alloc(2048 * sizeof(ushort16));

    dim3 blk(256);

    // ---- fused prep: x->bf16 | weight frags | cursor init (1057 blocks) ----
    prep_kernel<<<1057, blk, 0, stream>>>(
        (const float4*)x, (ushort4*)xb, NN * D / 4,
        W1l, W1r, W2l, W2r, Wf1, bfragL1, bfragL2, b2frag, bucketCursor);

    // ---- bucketed CSR build (fixed-capacity regions) ----
    multisplit_kernel<<<N_MS, dim3(1024), 0, stream>>>(src, dst, bucketCursor, edgesPacked);
    reorder_csr_kernel<<<NBUCK, blk, 0, stream>>>(
        edgesPacked, bucketCursor, rowBeg, deg, sortedSrc);

    // ---- layer 1: gather mean(xb) -> MFMA layer -> h1b ----
    gather_mean_kernel<<<2048, blk, 0, stream>>>(
        (const uint2*)xb, rowBeg, deg, sortedSrc, (uint2*)meanb, NN);
    sage_mfma_kernel<0><<<NTILE, blk, 0, stream>>>(
        xb, meanb, bfragL1, b2frag, b1l, bf1, Wf2, bf2, h1b, nullptr, NN);

    // ---- layer 2: gather mean(h1b) -> MFMA layer + fused MLP -> out ----
    gather_mean_kernel<<<2048, blk, 0, stream>>>(
        (const uint2*)h1b, rowBeg, deg, sortedSrc, (uint2*)meanb, NN);
    sage_mfma_kernel<1><<<NTILE, blk, 0, stream>>>(
        h1b, meanb, bfragL2, b2frag, b2l, bf1, Wf2, bf2, nullptr, out, NN);
}